// Round 5
// baseline (133.625 us; speedup 1.0000x reference)
//
#include <hip/hip_runtime.h>

#define B_DIM 512
#define F_DIM 128
#define L_DIM 1024
#define K_CLS 8
#define EPS 1e-5f
#define NROWS (B_DIM * F_DIM)          // 65536

typedef float  vf4  __attribute__((ext_vector_type(4)));
typedef ushort v4u16 __attribute__((ext_vector_type(4)));

// stats-area layout (floats, at `stats` base):
//   [0,1024) sum | [1024,2048) sumsq | [2048,3072) scale | [3072,4096) shift
#define WS_S2    (K_CLS * F_DIM)
#define WS_SCALE (2 * K_CLS * F_DIM)
#define WS_SHIFT (3 * K_CLS * F_DIM)

__device__ __forceinline__ ushort f2bf_rne(float f) {
    uint b = __float_as_uint(f);
    return (ushort)((b + 0x7FFFu + ((b >> 16) & 1u)) >> 16);
}

// ---- Pass 1: per-row sums + bf16 shadow copy of x. One wave per row. ----
__global__ __launch_bounds__(256) void cbn_stats_copy(const float* __restrict__ x,
                                                      const int* __restrict__ labels,
                                                      ushort* __restrict__ xb,
                                                      float* __restrict__ stats) {
    const int wave = threadIdx.x >> 6;
    const int lane = threadIdx.x & 63;
    const int row  = blockIdx.x * 4 + wave;    // [0, NROWS)
    const int b = row >> 7;
    const int f = row & (F_DIM - 1);

    const vf4* x4   = reinterpret_cast<const vf4*>(x) + (size_t)row * (L_DIM / 4);
    v4u16*     xb4  = reinterpret_cast<v4u16*>(xb)   + (size_t)row * (L_DIM / 4);

    float s = 0.f, s2 = 0.f;
#pragma unroll
    for (int i = 0; i < 4; ++i) {
        // non-temporal: x f32 is read-once; keep it out of L3 so the bf16 copy stays
        vf4 v = __builtin_nontemporal_load(&x4[i * 64 + lane]);
        s  += v.x + v.y + v.z + v.w;
        s2 += v.x * v.x + v.y * v.y + v.z * v.z + v.w * v.w;
        v4u16 u;
        u.x = f2bf_rne(v.x); u.y = f2bf_rne(v.y);
        u.z = f2bf_rne(v.z); u.w = f2bf_rne(v.w);
        xb4[i * 64 + lane] = u;                 // normal store -> L3-resident
    }
#pragma unroll
    for (int m = 32; m >= 1; m >>= 1) {
        s  += __shfl_xor(s, m);
        s2 += __shfl_xor(s2, m);
    }
    if (lane == 0) {
        const int k = labels[b];
        atomicAdd(&stats[k * F_DIM + f], s);
        atomicAdd(&stats[WS_S2 + k * F_DIM + f], s2);
    }
}

// ---- Fallback pass 1 (no copy) ----
__global__ __launch_bounds__(256) void cbn_stats(const float* __restrict__ x,
                                                 const int* __restrict__ labels,
                                                 float* __restrict__ stats) {
    const int wave = threadIdx.x >> 6;
    const int lane = threadIdx.x & 63;
    const int row  = blockIdx.x * 4 + wave;
    const int b = row >> 7;
    const int f = row & (F_DIM - 1);
    const vf4* x4 = reinterpret_cast<const vf4*>(x) + (size_t)row * (L_DIM / 4);
    float s = 0.f, s2 = 0.f;
#pragma unroll
    for (int i = 0; i < 4; ++i) {
        vf4 v = x4[i * 64 + lane];
        s  += v.x + v.y + v.z + v.w;
        s2 += v.x * v.x + v.y * v.y + v.z * v.z + v.w * v.w;
    }
#pragma unroll
    for (int m = 32; m >= 1; m >>= 1) {
        s  += __shfl_xor(s, m);
        s2 += __shfl_xor(s2, m);
    }
    if (lane == 0) {
        const int k = labels[b];
        atomicAdd(&stats[k * F_DIM + f], s);
        atomicAdd(&stats[WS_S2 + k * F_DIM + f], s2);
    }
}

// ---- Pass 2 finalize: one block, 1024 threads (= K*F). ----
__global__ __launch_bounds__(1024) void cbn_finalize(const int* __restrict__ labels,
                                                     const float* __restrict__ weight,
                                                     const float* __restrict__ bias,
                                                     float* __restrict__ stats) {
    __shared__ int cnt[K_CLS];
    const int t = threadIdx.x;
    if (t < K_CLS) cnt[t] = 0;
    __syncthreads();
    if (t < B_DIM) atomicAdd(&cnt[labels[t]], 1);
    __syncthreads();

    const int k = t >> 7;
    const float c = fmaxf((float)cnt[k] * (float)L_DIM, 1.0f);
    const float mean = stats[t] / c;
    const float var  = stats[WS_S2 + t] / c - mean * mean;
    const float inv  = rsqrtf(var + EPS);
    const float sc   = inv * weight[t];
    stats[WS_SCALE + t] = sc;
    stats[WS_SHIFT + t] = bias[t] - mean * sc;
}

// ---- Pass 3: apply from bf16 shadow copy (L3-hot). NT f32 stores. ----
#define APPLY_ROWS 4
__global__ __launch_bounds__(256) void cbn_apply_bf16(const ushort* __restrict__ xb,
                                                      const int* __restrict__ labels,
                                                      const float* __restrict__ stats,
                                                      float* __restrict__ y) {
    const int row0 = blockIdx.x * APPLY_ROWS;
#pragma unroll
    for (int it = 0; it < APPLY_ROWS; ++it) {
        const int row = row0 + it;                        // block-uniform
        const int b = row >> 7;
        const int f = row & (F_DIM - 1);
        const int k = labels[b];
        const float sc = stats[WS_SCALE + k * F_DIM + f];
        const float sh = stats[WS_SHIFT + k * F_DIM + f];

        const size_t i4 = (size_t)row * (L_DIM / 4) + threadIdx.x;
        v4u16 u = reinterpret_cast<const v4u16*>(xb)[i4];
        vf4 o;
        o.x = __uint_as_float((uint)u.x << 16) * sc + sh;
        o.y = __uint_as_float((uint)u.y << 16) * sc + sh;
        o.z = __uint_as_float((uint)u.z << 16) * sc + sh;
        o.w = __uint_as_float((uint)u.w << 16) * sc + sh;
        __builtin_nontemporal_store(o, &reinterpret_cast<vf4*>(y)[i4]);
    }
}

// ---- Fallback pass 3: re-read f32 x backward, NT stores. ----
__global__ __launch_bounds__(256) void cbn_apply_f32(const float* __restrict__ x,
                                                     const int* __restrict__ labels,
                                                     const float* __restrict__ stats,
                                                     float* __restrict__ y) {
    const int nBlocks = NROWS / APPLY_ROWS;
    const int blk = nBlocks - 1 - blockIdx.x;
    const int row0 = blk * APPLY_ROWS;
#pragma unroll
    for (int it = 0; it < APPLY_ROWS; ++it) {
        const int row = row0 + it;
        const int b = row >> 7;
        const int f = row & (F_DIM - 1);
        const int k = labels[b];
        const float sc = stats[WS_SCALE + k * F_DIM + f];
        const float sh = stats[WS_SHIFT + k * F_DIM + f];
        const size_t i4 = (size_t)row * (L_DIM / 4) + threadIdx.x;
        vf4 v = reinterpret_cast<const vf4*>(x)[i4];
        vf4 o;
        o.x = v.x * sc + sh;
        o.y = v.y * sc + sh;
        o.z = v.z * sc + sh;
        o.w = v.w * sc + sh;
        __builtin_nontemporal_store(o, &reinterpret_cast<vf4*>(y)[i4]);
    }
}

extern "C" void kernel_launch(void* const* d_in, const int* in_sizes, int n_in,
                              void* d_out, int out_size, void* d_ws, size_t ws_size,
                              hipStream_t stream) {
    const float* x      = (const float*)d_in[0];
    const int*   labels = (const int*)d_in[1];
    const float* weight = (const float*)d_in[2];
    const float* bias   = (const float*)d_in[3];
    float* y = (float*)d_out;

    const size_t XB_BYTES = (size_t)NROWS * L_DIM * 2;      // 128 MiB
    const size_t NEEDED   = XB_BYTES + 4 * K_CLS * F_DIM * sizeof(float);

    if (ws_size >= NEEDED) {
        ushort* xb    = (ushort*)d_ws;
        float*  stats = (float*)((char*)d_ws + XB_BYTES);
        hipMemsetAsync(stats, 0, 2 * K_CLS * F_DIM * sizeof(float), stream);
        cbn_stats_copy<<<NROWS / 4, 256, 0, stream>>>(x, labels, xb, stats);
        cbn_finalize<<<1, 1024, 0, stream>>>(labels, weight, bias, stats);
        cbn_apply_bf16<<<NROWS / APPLY_ROWS, 256, 0, stream>>>(xb, labels, stats, y);
    } else {
        float* stats = (float*)d_ws;
        hipMemsetAsync(stats, 0, 2 * K_CLS * F_DIM * sizeof(float), stream);
        cbn_stats<<<NROWS / 4, 256, 0, stream>>>(x, labels, stats);
        cbn_finalize<<<1, 1024, 0, stream>>>(labels, weight, bias, stats);
        cbn_apply_f32<<<NROWS / APPLY_ROWS, 256, 0, stream>>>(x, labels, stats, y);
    }
}

// Round 6
// 126.792 us; speedup vs baseline: 1.0539x; 1.0539x over previous
//
#include <hip/hip_runtime.h>

#define B_DIM 512
#define F_DIM 128
#define L_DIM 1024
#define K_CLS 8
#define EPS 1e-5f
#define NROWS (B_DIM * F_DIM)          // 65536

typedef float  vf4  __attribute__((ext_vector_type(4)));
typedef ushort v4u16 __attribute__((ext_vector_type(4)));

// stats region layout (floats), placed after xb in d_ws:
//   [0, NROWS)              psum[f*512 + b]
//   [NROWS, 2*NROWS)        psq [f*512 + b]
//   [2*NROWS, +1024)        scale[k*128+f]
//   [2*NROWS+1024, +1024)   shift[k*128+f]
#define ST_SQ    NROWS
#define ST_SCALE (2 * NROWS)
#define ST_SHIFT (2 * NROWS + K_CLS * F_DIM)

__device__ __forceinline__ ushort f2bf_rne(float f) {
    uint b = __float_as_uint(f);
    return (ushort)((b + 0x7FFFu + ((b >> 16) & 1u)) >> 16);
}

// ---- Pass 1: per-row sums + bf16 shadow copy. One wave per row. ----
// x read non-temporally (read-once); xb written normally (want MALL-resident);
// partials written to [f][b] layout (no atomics, no pre-zero needed).
__global__ __launch_bounds__(256) void cbn_stats_copy(const float* __restrict__ x,
                                                      ushort* __restrict__ xb,
                                                      float* __restrict__ st) {
    const int wave = threadIdx.x >> 6;
    const int lane = threadIdx.x & 63;
    const int row  = blockIdx.x * 4 + wave;    // [0, NROWS)
    const int b = row >> 7;
    const int f = row & (F_DIM - 1);

    const vf4* x4  = reinterpret_cast<const vf4*>(x) + (size_t)row * (L_DIM / 4);
    v4u16*     xb4 = reinterpret_cast<v4u16*>(xb)    + (size_t)row * (L_DIM / 4);

    float s = 0.f, s2 = 0.f;
#pragma unroll
    for (int i = 0; i < 4; ++i) {
        vf4 v = __builtin_nontemporal_load(&x4[i * 64 + lane]);
        s  += v.x + v.y + v.z + v.w;
        s2 += v.x * v.x + v.y * v.y + v.z * v.z + v.w * v.w;
        v4u16 u;
        u.x = f2bf_rne(v.x); u.y = f2bf_rne(v.y);
        u.z = f2bf_rne(v.z); u.w = f2bf_rne(v.w);
        xb4[i * 64 + lane] = u;
    }
#pragma unroll
    for (int m = 32; m >= 1; m >>= 1) {
        s  += __shfl_xor(s, m);
        s2 += __shfl_xor(s2, m);
    }
    if (lane == 0) {
        st[f * B_DIM + b]         = s;
        st[ST_SQ + f * B_DIM + b] = s2;
    }
}

// ---- Fallback pass 1 (no copy) ----
__global__ __launch_bounds__(256) void cbn_stats(const float* __restrict__ x,
                                                 float* __restrict__ st) {
    const int wave = threadIdx.x >> 6;
    const int lane = threadIdx.x & 63;
    const int row  = blockIdx.x * 4 + wave;
    const int b = row >> 7;
    const int f = row & (F_DIM - 1);
    const vf4* x4 = reinterpret_cast<const vf4*>(x) + (size_t)row * (L_DIM / 4);
    float s = 0.f, s2 = 0.f;
#pragma unroll
    for (int i = 0; i < 4; ++i) {
        vf4 v = x4[i * 64 + lane];
        s  += v.x + v.y + v.z + v.w;
        s2 += v.x * v.x + v.y * v.y + v.z * v.z + v.w * v.w;
    }
#pragma unroll
    for (int m = 32; m >= 1; m >>= 1) {
        s  += __shfl_xor(s, m);
        s2 += __shfl_xor(s2, m);
    }
    if (lane == 0) {
        st[f * B_DIM + b]         = s;
        st[ST_SQ + f * B_DIM + b] = s2;
    }
}

// ---- Pass 2 finalize: 128 blocks (one per f) x 512 threads (one per b). ----
__global__ __launch_bounds__(512) void cbn_finalize(const int* __restrict__ labels,
                                                    const float* __restrict__ weight,
                                                    const float* __restrict__ bias,
                                                    float* __restrict__ st) {
    __shared__ float ssum[K_CLS], ssq[K_CLS];
    __shared__ int   cnt[K_CLS];
    const int f = blockIdx.x;
    const int b = threadIdx.x;
    if (b < K_CLS) { ssum[b] = 0.f; ssq[b] = 0.f; cnt[b] = 0; }
    __syncthreads();

    const int k = labels[b];
    atomicAdd(&ssum[k], st[f * B_DIM + b]);
    atomicAdd(&ssq[k],  st[ST_SQ + f * B_DIM + b]);
    atomicAdd(&cnt[k], 1);
    __syncthreads();

    if (b < K_CLS) {
        const float c = fmaxf((float)cnt[b] * (float)L_DIM, 1.0f);
        const float mean = ssum[b] / c;
        const float var  = ssq[b] / c - mean * mean;
        const float inv  = rsqrtf(var + EPS);
        const float sc   = inv * weight[b * F_DIM + f];
        st[ST_SCALE + b * F_DIM + f] = sc;
        st[ST_SHIFT + b * F_DIM + f] = bias[b * F_DIM + f] - mean * sc;
    }
}

// ---- Pass 3: apply from bf16 shadow, BACKWARD (freshest xb first). ----
#define APPLY_ROWS 4
__global__ __launch_bounds__(256) void cbn_apply_bf16(const ushort* __restrict__ xb,
                                                      const int* __restrict__ labels,
                                                      const float* __restrict__ st,
                                                      float* __restrict__ y) {
    const int nBlocks = NROWS / APPLY_ROWS;
    const int blk = nBlocks - 1 - blockIdx.x;             // reversed
    const int row0 = blk * APPLY_ROWS;
#pragma unroll
    for (int it = 0; it < APPLY_ROWS; ++it) {
        const int row = row0 + it;                        // block-uniform
        const int b = row >> 7;
        const int f = row & (F_DIM - 1);
        const int k = labels[b];
        const float sc = st[ST_SCALE + k * F_DIM + f];
        const float sh = st[ST_SHIFT + k * F_DIM + f];

        const size_t i4 = (size_t)row * (L_DIM / 4) + threadIdx.x;
        v4u16 u = reinterpret_cast<const v4u16*>(xb)[i4];
        vf4 o;
        o.x = __uint_as_float((uint)u.x << 16) * sc + sh;
        o.y = __uint_as_float((uint)u.y << 16) * sc + sh;
        o.z = __uint_as_float((uint)u.z << 16) * sc + sh;
        o.w = __uint_as_float((uint)u.w << 16) * sc + sh;
        __builtin_nontemporal_store(o, &reinterpret_cast<vf4*>(y)[i4]);
    }
}

// ---- Fallback pass 3: re-read f32 x backward, NT stores. ----
__global__ __launch_bounds__(256) void cbn_apply_f32(const float* __restrict__ x,
                                                     const int* __restrict__ labels,
                                                     const float* __restrict__ st,
                                                     float* __restrict__ y) {
    const int nBlocks = NROWS / APPLY_ROWS;
    const int blk = nBlocks - 1 - blockIdx.x;
    const int row0 = blk * APPLY_ROWS;
#pragma unroll
    for (int it = 0; it < APPLY_ROWS; ++it) {
        const int row = row0 + it;
        const int b = row >> 7;
        const int f = row & (F_DIM - 1);
        const int k = labels[b];
        const float sc = st[ST_SCALE + k * F_DIM + f];
        const float sh = st[ST_SHIFT + k * F_DIM + f];
        const size_t i4 = (size_t)row * (L_DIM / 4) + threadIdx.x;
        vf4 v = reinterpret_cast<const vf4*>(x)[i4];
        vf4 o;
        o.x = v.x * sc + sh;
        o.y = v.y * sc + sh;
        o.z = v.z * sc + sh;
        o.w = v.w * sc + sh;
        __builtin_nontemporal_store(o, &reinterpret_cast<vf4*>(y)[i4]);
    }
}

extern "C" void kernel_launch(void* const* d_in, const int* in_sizes, int n_in,
                              void* d_out, int out_size, void* d_ws, size_t ws_size,
                              hipStream_t stream) {
    const float* x      = (const float*)d_in[0];
    const int*   labels = (const int*)d_in[1];
    const float* weight = (const float*)d_in[2];
    const float* bias   = (const float*)d_in[3];
    float* y = (float*)d_out;

    const size_t XB_BYTES = (size_t)NROWS * L_DIM * 2;                       // 128 MiB
    const size_t ST_BYTES = (2 * NROWS + 2 * K_CLS * F_DIM) * sizeof(float); // ~520 KiB

    if (ws_size >= XB_BYTES + ST_BYTES) {
        ushort* xb = (ushort*)d_ws;
        float*  st = (float*)((char*)d_ws + XB_BYTES);
        cbn_stats_copy<<<NROWS / 4, 256, 0, stream>>>(x, xb, st);
        cbn_finalize<<<F_DIM, 512, 0, stream>>>(labels, weight, bias, st);
        cbn_apply_bf16<<<NROWS / APPLY_ROWS, 256, 0, stream>>>(xb, labels, st, y);
    } else {
        float* st = (float*)d_ws;
        cbn_stats<<<NROWS / 4, 256, 0, stream>>>(x, st);
        cbn_finalize<<<F_DIM, 512, 0, stream>>>(labels, weight, bias, st);
        cbn_apply_f32<<<NROWS / APPLY_ROWS, 256, 0, stream>>>(x, labels, st, y);
    }
}